// Round 1
// baseline (508.929 us; speedup 1.0000x reference)
//
#include <hip/hip_runtime.h>

namespace {

constexpr int Ldim = 6400;   // rows (h0*w0)
constexpr int Sdim = 6400;   // cols (h1*w1)
constexpr int Cdim = 256;    // feature dim
constexpr float INV_CT = 0.0390625f;  // 1/(256*0.1) == 5/128, exact
constexpr float THR = 0.2f;

constexpr int BM = 128, BN = 128, BK = 32;
constexpr int LDT = BM + 4;  // LDS row stride (132 floats = 528 B, 16B-aligned)

__device__ __forceinline__ void atomicMaxPosF(float* addr, float v) {
  // valid for non-negative floats: uint bit order == float order
  atomicMax(reinterpret_cast<unsigned int*>(addr), __float_as_uint(v));
}

__device__ __forceinline__ bool valid80(int idx) {
  const int i = idx / 80;
  const int j = idx - i * 80;
  return (i >= 2) & (i < 78) & (j >= 2) & (j < 78);
}

// --- K1: sim = x0 @ x1^T * INV_CT, written to `sim`; also accumulate
//         Rsum[l] = sum_s exp(sim[l,s]) and Csum[s] = sum_l exp(sim[l,s]).
__global__ __launch_bounds__(256)
void k_gemm_stats(const float* __restrict__ A, const float* __restrict__ B,
                  float* __restrict__ sim, float* __restrict__ Rsum,
                  float* __restrict__ Csum) {
  __shared__ float As[BK][LDT];
  __shared__ float Bs[BK][LDT];
  __shared__ float csum_l[BN];

  const int tid = threadIdx.x;
  const int tx = tid & 15;
  const int ty = tid >> 4;
  const int nbx = Sdim / BN;  // 50
  const int bx = blockIdx.x % nbx;
  const int by = blockIdx.x / nbx;
  const int m0 = by * BM, n0 = bx * BN;

  float acc[8][8];
#pragma unroll
  for (int i = 0; i < 8; ++i)
#pragma unroll
    for (int j = 0; j < 8; ++j) acc[i][j] = 0.f;

  const int lr = tid >> 3;       // 0..31
  const int lk = (tid & 7) * 4;  // 0,4,...,28

  for (int k0 = 0; k0 < Cdim; k0 += BK) {
    __syncthreads();  // protect LDS reuse from previous iteration's reads
#pragma unroll
    for (int p = 0; p < 4; ++p) {
      const int r = lr + p * 32;
      float4 a = *reinterpret_cast<const float4*>(
          &A[(size_t)(m0 + r) * Cdim + k0 + lk]);
      As[lk + 0][r] = a.x; As[lk + 1][r] = a.y;
      As[lk + 2][r] = a.z; As[lk + 3][r] = a.w;
      float4 b = *reinterpret_cast<const float4*>(
          &B[(size_t)(n0 + r) * Cdim + k0 + lk]);
      Bs[lk + 0][r] = b.x; Bs[lk + 1][r] = b.y;
      Bs[lk + 2][r] = b.z; Bs[lk + 3][r] = b.w;
    }
    __syncthreads();
#pragma unroll
    for (int k = 0; k < BK; ++k) {
      float av[8], bv[8];
      const float4 a0 = *reinterpret_cast<const float4*>(&As[k][ty * 4]);
      const float4 a1 = *reinterpret_cast<const float4*>(&As[k][ty * 4 + 64]);
      const float4 b0 = *reinterpret_cast<const float4*>(&Bs[k][tx * 4]);
      const float4 b1 = *reinterpret_cast<const float4*>(&Bs[k][tx * 4 + 64]);
      av[0] = a0.x; av[1] = a0.y; av[2] = a0.z; av[3] = a0.w;
      av[4] = a1.x; av[5] = a1.y; av[6] = a1.z; av[7] = a1.w;
      bv[0] = b0.x; bv[1] = b0.y; bv[2] = b0.z; bv[3] = b0.w;
      bv[4] = b1.x; bv[5] = b1.y; bv[6] = b1.z; bv[7] = b1.w;
#pragma unroll
      for (int i = 0; i < 8; ++i)
#pragma unroll
        for (int j = 0; j < 8; ++j) acc[i][j] = fmaf(av[i], bv[j], acc[i][j]);
    }
  }

  // scale to sim
#pragma unroll
  for (int i = 0; i < 8; ++i)
#pragma unroll
    for (int j = 0; j < 8; ++j) acc[i][j] *= INV_CT;

  // write sim tile (coalesced float4)
#pragma unroll
  for (int i = 0; i < 8; ++i) {
    const int row = m0 + ty * 4 + (i & 3) + (i >> 2) * 64;
    const float4 v0 = make_float4(acc[i][0], acc[i][1], acc[i][2], acc[i][3]);
    const float4 v1 = make_float4(acc[i][4], acc[i][5], acc[i][6], acc[i][7]);
    *reinterpret_cast<float4*>(&sim[(size_t)row * Sdim + n0 + tx * 4]) = v0;
    *reinterpret_cast<float4*>(&sim[(size_t)row * Sdim + n0 + 64 + tx * 4]) = v1;
  }

  // row sums of exp: reduce across tx (16 lanes of the wave), then atomic
#pragma unroll
  for (int i = 0; i < 8; ++i) {
    float re = 0.f;
#pragma unroll
    for (int j = 0; j < 8; ++j) re += expf(acc[i][j]);
    re += __shfl_xor(re, 1);
    re += __shfl_xor(re, 2);
    re += __shfl_xor(re, 4);
    re += __shfl_xor(re, 8);
    if (tx == 0) {
      const int row = m0 + ty * 4 + (i & 3) + (i >> 2) * 64;
      atomicAdd(&Rsum[row], re);
    }
  }

  // col sums of exp via LDS
  if (tid < BN) csum_l[tid] = 0.f;
  __syncthreads();
#pragma unroll
  for (int j = 0; j < 8; ++j) {
    float ce = 0.f;
#pragma unroll
    for (int i = 0; i < 8; ++i) ce += expf(acc[i][j]);
    const int col = tx * 4 + (j & 3) + (j >> 2) * 64;
    atomicAdd(&csum_l[col], ce);
  }
  __syncthreads();
  if (tid < BN) atomicAdd(&Csum[n0 + tid], csum_l[tid]);
}

// --- K2: conf = exp(2*sim)/(Rsum[l]*Csum[s]) written IN PLACE over sim;
//         also reduce per-row / per-col max of conf.
__global__ __launch_bounds__(256)
void k_conf_max(float* __restrict__ simconf, const float* __restrict__ Rsum,
                const float* __restrict__ Csum, float* __restrict__ RM,
                float* __restrict__ CM) {
  __shared__ float cml[64];
  const int tid = threadIdx.x;
  const int tx = tid & 15;
  const int ty = tid >> 4;
  const int nbx = Sdim / 64;  // 100
  const int bx = blockIdx.x % nbx;
  const int by = blockIdx.x / nbx;
  const int m0 = by * 64, n0 = bx * 64;

  if (tid < 64) cml[tid] = 0.f;
  __syncthreads();

  const float4 cs4 = *reinterpret_cast<const float4*>(&Csum[n0 + tx * 4]);
  float cmax0 = 0.f, cmax1 = 0.f, cmax2 = 0.f, cmax3 = 0.f;

#pragma unroll
  for (int i = 0; i < 4; ++i) {
    const int row = m0 + ty * 4 + i;
    const float rs = Rsum[row];
    float* p = &simconf[(size_t)row * Sdim + n0 + tx * 4];
    float4 s = *reinterpret_cast<float4*>(p);
    float4 c;
    c.x = expf(2.f * s.x) / (rs * cs4.x);
    c.y = expf(2.f * s.y) / (rs * cs4.y);
    c.z = expf(2.f * s.z) / (rs * cs4.z);
    c.w = expf(2.f * s.w) / (rs * cs4.w);
    *reinterpret_cast<float4*>(p) = c;

    float rm = fmaxf(fmaxf(c.x, c.y), fmaxf(c.z, c.w));
    rm = fmaxf(rm, __shfl_xor(rm, 1));
    rm = fmaxf(rm, __shfl_xor(rm, 2));
    rm = fmaxf(rm, __shfl_xor(rm, 4));
    rm = fmaxf(rm, __shfl_xor(rm, 8));
    if (tx == 0) atomicMaxPosF(&RM[row], rm);

    cmax0 = fmaxf(cmax0, c.x);
    cmax1 = fmaxf(cmax1, c.y);
    cmax2 = fmaxf(cmax2, c.z);
    cmax3 = fmaxf(cmax3, c.w);
  }
  atomicMax(reinterpret_cast<unsigned int*>(&cml[tx * 4 + 0]), __float_as_uint(cmax0));
  atomicMax(reinterpret_cast<unsigned int*>(&cml[tx * 4 + 1]), __float_as_uint(cmax1));
  atomicMax(reinterpret_cast<unsigned int*>(&cml[tx * 4 + 2]), __float_as_uint(cmax2));
  atomicMax(reinterpret_cast<unsigned int*>(&cml[tx * 4 + 3]), __float_as_uint(cmax3));
  __syncthreads();
  if (tid < 64) atomicMaxPosF(&CM[n0 + tid], cml[tid]);
}

// --- K3: out = conf * (conf>THR & margin & conf==rowmax & conf==colmax), in place
__global__ __launch_bounds__(256)
void k_mask(float* __restrict__ conf, const float* __restrict__ RM,
            const float* __restrict__ CM) {
  const int g = blockIdx.x * 256 + threadIdx.x;  // 0 .. 6400*1600-1
  const int l = g / 1600;
  const int s0 = (g - l * 1600) * 4;
  float* p = &conf[(size_t)l * Sdim + s0];
  float4 c = *reinterpret_cast<float4*>(p);
  const bool vl = valid80(l);
  const float rm = RM[l];
  const float4 cm = *reinterpret_cast<const float4*>(&CM[s0]);

  c.x = (vl && valid80(s0 + 0) && c.x > THR && c.x == rm && c.x == cm.x) ? c.x : 0.f;
  c.y = (vl && valid80(s0 + 1) && c.y > THR && c.y == rm && c.y == cm.y) ? c.y : 0.f;
  c.z = (vl && valid80(s0 + 2) && c.z > THR && c.z == rm && c.z == cm.z) ? c.z : 0.f;
  c.w = (vl && valid80(s0 + 3) && c.w > THR && c.w == rm && c.w == cm.w) ? c.w : 0.f;

  *reinterpret_cast<float4*>(p) = c;
}

}  // namespace

extern "C" void kernel_launch(void* const* d_in, const int* in_sizes, int n_in,
                              void* d_out, int out_size, void* d_ws, size_t ws_size,
                              hipStream_t stream) {
  (void)in_sizes; (void)n_in; (void)out_size; (void)ws_size;
  const float* x0 = reinterpret_cast<const float*>(d_in[0]);
  const float* x1 = reinterpret_cast<const float*>(d_in[1]);
  float* out = reinterpret_cast<float*>(d_out);

  float* Rsum = reinterpret_cast<float*>(d_ws);
  float* Csum = Rsum + Ldim;
  float* RM = Csum + Sdim;
  float* CM = RM + Ldim;

  // zero the stats arrays (sums -> 0, maxes of positive floats -> 0)
  hipMemsetAsync(d_ws, 0, sizeof(float) * (size_t)(2 * Ldim + 2 * Sdim), stream);

  k_gemm_stats<<<(Ldim / BM) * (Sdim / BN), 256, 0, stream>>>(x0, x1, out, Rsum, Csum);
  k_conf_max<<<(Ldim / 64) * (Sdim / 64), 256, 0, stream>>>(out, Rsum, Csum, RM, CM);
  k_mask<<<(Ldim * Sdim) / (4 * 256), 256, 0, stream>>>(out, RM, CM);
}

// Round 2
// 387.519 us; speedup vs baseline: 1.3133x; 1.3133x over previous
//
#include <hip/hip_runtime.h>

namespace {

constexpr int Ldim = 6400;   // rows (h0*w0)
constexpr int Sdim = 6400;   // cols (h1*w1)
constexpr int Cdim = 256;    // feature dim
constexpr float INV_CT = 0.0390625f;  // 1/(256*0.1) == 5/128, exact
constexpr float THR = 0.2f;

constexpr int BM = 128, BN = 128, BK = 32;
constexpr int PITCH = 40;  // bf16 elements per LDS row (80 B, 16B-aligned, bank-stride 20)

typedef __attribute__((ext_vector_type(8))) short short8;
typedef __attribute__((ext_vector_type(4))) float f32x4;

__device__ __forceinline__ void atomicMaxPosF(float* addr, float v) {
  // valid for non-negative floats: uint bit order == float order
  atomicMax(reinterpret_cast<unsigned int*>(addr), __float_as_uint(v));
}

__device__ __forceinline__ bool valid80(int idx) {
  const int i = idx / 80;
  const int j = idx - i * 80;
  return (i >= 2) & (i < 78) & (j >= 2) & (j < 78);
}

// round-to-nearest-even fp32 -> bf16 bits (inputs are finite normals)
__device__ __forceinline__ unsigned short f2bf(float v) {
  unsigned u = __float_as_uint(v);
  return (unsigned short)((u + 0x7fffu + ((u >> 16) & 1u)) >> 16);
}

__device__ __forceinline__ void splitbf(float v, unsigned short& h, unsigned short& l) {
  h = f2bf(v);
  float back = __uint_as_float(((unsigned)h) << 16);
  l = f2bf(v - back);  // exact subtraction (Sterbenz-like), captures next 8 bits
}

// conf from sim + stats. MUST be the single definition used by K2 and K3 so
// the == comparisons against the reduced maxes are bitwise-consistent.
__device__ __forceinline__ float4 conf4(float4 s, float rs, const float4& cs) {
  float4 c;
  c.x = expf(2.f * s.x) / (rs * cs.x);
  c.y = expf(2.f * s.y) / (rs * cs.y);
  c.z = expf(2.f * s.z) / (rs * cs.z);
  c.w = expf(2.f * s.w) / (rs * cs.w);
  return c;
}

// --- K1: sim = x0 @ x1^T * INV_CT via bf16x3 split MFMA; writes sim and
//         accumulates Rsum[l] = sum_s exp(sim), Csum[s] = sum_l exp(sim).
__global__ __launch_bounds__(256)
void k_gemm_mfma(const float* __restrict__ A, const float* __restrict__ B,
                 float* __restrict__ sim, float* __restrict__ Rsum,
                 float* __restrict__ Csum) {
  __shared__ unsigned short Ah[BM][PITCH], Al[BM][PITCH];
  __shared__ unsigned short Bh[BN][PITCH], Bl[BN][PITCH];

  const int tid = threadIdx.x;
  const int lane = tid & 63;
  const int wave = tid >> 6;        // 4 waves, 2x2 of 64x64 sub-tiles
  const int wr = wave >> 1, wc = wave & 1;
  const int bx = blockIdx.x % (Sdim / BN);
  const int by = blockIdx.x / (Sdim / BN);
  const int m0 = by * BM, n0 = bx * BN;

  const int lg = lane >> 4;         // 0..3 : k-group / row-group
  const int ll = lane & 15;         // 0..15: row (A-frag) / col (B-frag)

  f32x4 acc[4][4];
#pragma unroll
  for (int mi = 0; mi < 4; ++mi)
#pragma unroll
    for (int ni = 0; ni < 4; ++ni) acc[mi][ni] = (f32x4){0.f, 0.f, 0.f, 0.f};

  const int srow = tid >> 3;        // 0..31
  const int kq = tid & 7;           // float4 index within BK=32

  for (int k0 = 0; k0 < Cdim; k0 += BK) {
    __syncthreads();  // protect LDS from previous iteration's readers
#pragma unroll
    for (int p = 0; p < 4; ++p) {
      const int r = srow + p * 32;
      const float4 av = *reinterpret_cast<const float4*>(
          &A[(size_t)(m0 + r) * Cdim + k0 + kq * 4]);
      const float4 bv = *reinterpret_cast<const float4*>(
          &B[(size_t)(n0 + r) * Cdim + k0 + kq * 4]);
      ushort4 ah, al, bh, bl;
      splitbf(av.x, ah.x, al.x); splitbf(av.y, ah.y, al.y);
      splitbf(av.z, ah.z, al.z); splitbf(av.w, ah.w, al.w);
      splitbf(bv.x, bh.x, bl.x); splitbf(bv.y, bh.y, bl.y);
      splitbf(bv.z, bh.z, bl.z); splitbf(bv.w, bh.w, bl.w);
      *reinterpret_cast<ushort4*>(&Ah[r][kq * 4]) = ah;
      *reinterpret_cast<ushort4*>(&Al[r][kq * 4]) = al;
      *reinterpret_cast<ushort4*>(&Bh[r][kq * 4]) = bh;
      *reinterpret_cast<ushort4*>(&Bl[r][kq * 4]) = bl;
    }
    __syncthreads();

    short8 af[4], bf_[4], tf[4];
#pragma unroll
    for (int mi = 0; mi < 4; ++mi)
      af[mi] = *reinterpret_cast<const short8*>(&Ah[wr * 64 + mi * 16 + ll][lg * 8]);
#pragma unroll
    for (int ni = 0; ni < 4; ++ni)
      bf_[ni] = *reinterpret_cast<const short8*>(&Bh[wc * 64 + ni * 16 + ll][lg * 8]);
    // hi * hi
#pragma unroll
    for (int mi = 0; mi < 4; ++mi)
#pragma unroll
      for (int ni = 0; ni < 4; ++ni)
        acc[mi][ni] = __builtin_amdgcn_mfma_f32_16x16x32_bf16(af[mi], bf_[ni], acc[mi][ni], 0, 0, 0);
    // hi * lo
#pragma unroll
    for (int ni = 0; ni < 4; ++ni)
      tf[ni] = *reinterpret_cast<const short8*>(&Bl[wc * 64 + ni * 16 + ll][lg * 8]);
#pragma unroll
    for (int mi = 0; mi < 4; ++mi)
#pragma unroll
      for (int ni = 0; ni < 4; ++ni)
        acc[mi][ni] = __builtin_amdgcn_mfma_f32_16x16x32_bf16(af[mi], tf[ni], acc[mi][ni], 0, 0, 0);
    // lo * hi
#pragma unroll
    for (int mi = 0; mi < 4; ++mi)
      tf[mi] = *reinterpret_cast<const short8*>(&Al[wr * 64 + mi * 16 + ll][lg * 8]);
#pragma unroll
    for (int mi = 0; mi < 4; ++mi)
#pragma unroll
      for (int ni = 0; ni < 4; ++ni)
        acc[mi][ni] = __builtin_amdgcn_mfma_f32_16x16x32_bf16(tf[mi], bf_[ni], acc[mi][ni], 0, 0, 0);
  }

  // scale: sim = acc * INV_CT
#pragma unroll
  for (int mi = 0; mi < 4; ++mi)
#pragma unroll
    for (int ni = 0; ni < 4; ++ni) acc[mi][ni] *= INV_CT;

  // write sim. C/D layout: col = lane&15, row = (lane>>4)*4 + reg  [m89/m91]
#pragma unroll
  for (int mi = 0; mi < 4; ++mi)
#pragma unroll
    for (int r = 0; r < 4; ++r) {
      const int row = m0 + wr * 64 + mi * 16 + lg * 4 + r;
#pragma unroll
      for (int ni = 0; ni < 4; ++ni) {
        const int col = n0 + wc * 64 + ni * 16 + ll;
        sim[(size_t)row * Sdim + col] = acc[mi][ni][r];
      }
    }

  // exp sums: each exp computed once, feeds row sum (shuffle over 16 lanes)
  // and col partials (register accumulate, then shuffle over row-groups).
  float colp[4] = {0.f, 0.f, 0.f, 0.f};
#pragma unroll
  for (int mi = 0; mi < 4; ++mi)
#pragma unroll
    for (int r = 0; r < 4; ++r) {
      float re = 0.f;
#pragma unroll
      for (int ni = 0; ni < 4; ++ni) {
        const float e = expf(acc[mi][ni][r]);
        re += e;
        colp[ni] += e;
      }
      re += __shfl_xor(re, 1);
      re += __shfl_xor(re, 2);
      re += __shfl_xor(re, 4);
      re += __shfl_xor(re, 8);
      if (ll == 0)
        atomicAdd(&Rsum[m0 + wr * 64 + mi * 16 + lg * 4 + r], re);
    }
#pragma unroll
  for (int ni = 0; ni < 4; ++ni) {
    float c = colp[ni];
    c += __shfl_xor(c, 16);
    c += __shfl_xor(c, 32);
    if (lane < 16) atomicAdd(&Csum[n0 + wc * 64 + ni * 16 + lane], c);
  }
}

// --- K2: compute conf from sim (no write-back), reduce per-row/per-col max.
__global__ __launch_bounds__(256)
void k_conf_max(const float* __restrict__ sim, const float* __restrict__ Rsum,
                const float* __restrict__ Csum, float* __restrict__ RM,
                float* __restrict__ CM) {
  __shared__ float cml[64];
  const int tid = threadIdx.x;
  const int tx = tid & 15;
  const int ty = tid >> 4;
  const int nbx = Sdim / 64;  // 100
  const int bx = blockIdx.x % nbx;
  const int by = blockIdx.x / nbx;
  const int m0 = by * 64, n0 = bx * 64;

  if (tid < 64) cml[tid] = 0.f;
  __syncthreads();

  const float4 cs4 = *reinterpret_cast<const float4*>(&Csum[n0 + tx * 4]);
  float cmax0 = 0.f, cmax1 = 0.f, cmax2 = 0.f, cmax3 = 0.f;

#pragma unroll
  for (int i = 0; i < 4; ++i) {
    const int row = m0 + ty * 4 + i;
    const float rs = Rsum[row];
    const float4 s = *reinterpret_cast<const float4*>(&sim[(size_t)row * Sdim + n0 + tx * 4]);
    const float4 c = conf4(s, rs, cs4);

    float rm = fmaxf(fmaxf(c.x, c.y), fmaxf(c.z, c.w));
    rm = fmaxf(rm, __shfl_xor(rm, 1));
    rm = fmaxf(rm, __shfl_xor(rm, 2));
    rm = fmaxf(rm, __shfl_xor(rm, 4));
    rm = fmaxf(rm, __shfl_xor(rm, 8));
    if (tx == 0) atomicMaxPosF(&RM[row], rm);

    cmax0 = fmaxf(cmax0, c.x);
    cmax1 = fmaxf(cmax1, c.y);
    cmax2 = fmaxf(cmax2, c.z);
    cmax3 = fmaxf(cmax3, c.w);
  }
  atomicMax(reinterpret_cast<unsigned int*>(&cml[tx * 4 + 0]), __float_as_uint(cmax0));
  atomicMax(reinterpret_cast<unsigned int*>(&cml[tx * 4 + 1]), __float_as_uint(cmax1));
  atomicMax(reinterpret_cast<unsigned int*>(&cml[tx * 4 + 2]), __float_as_uint(cmax2));
  atomicMax(reinterpret_cast<unsigned int*>(&cml[tx * 4 + 3]), __float_as_uint(cmax3));
  __syncthreads();
  if (tid < 64) atomicMaxPosF(&CM[n0 + tid], cml[tid]);
}

// --- K3: recompute conf (bitwise identical to K2), mask, write output in place.
__global__ __launch_bounds__(256)
void k_mask(float* __restrict__ simconf, const float* __restrict__ Rsum,
            const float* __restrict__ Csum, const float* __restrict__ RM,
            const float* __restrict__ CM) {
  const int g = blockIdx.x * 256 + threadIdx.x;  // 0 .. 6400*1600-1
  const int l = g / 1600;
  const int s0 = (g - l * 1600) * 4;
  float* p = &simconf[(size_t)l * Sdim + s0];
  const float4 s = *reinterpret_cast<const float4*>(p);
  const float rs = Rsum[l];
  const float4 cs = *reinterpret_cast<const float4*>(&Csum[s0]);
  float4 c = conf4(s, rs, cs);

  const bool vl = valid80(l);
  const float rm = RM[l];
  const float4 cm = *reinterpret_cast<const float4*>(&CM[s0]);

  c.x = (vl && valid80(s0 + 0) && c.x > THR && c.x == rm && c.x == cm.x) ? c.x : 0.f;
  c.y = (vl && valid80(s0 + 1) && c.y > THR && c.y == rm && c.y == cm.y) ? c.y : 0.f;
  c.z = (vl && valid80(s0 + 2) && c.z > THR && c.z == rm && c.z == cm.z) ? c.z : 0.f;
  c.w = (vl && valid80(s0 + 3) && c.w > THR && c.w == rm && c.w == cm.w) ? c.w : 0.f;

  *reinterpret_cast<float4*>(p) = c;
}

}  // namespace

extern "C" void kernel_launch(void* const* d_in, const int* in_sizes, int n_in,
                              void* d_out, int out_size, void* d_ws, size_t ws_size,
                              hipStream_t stream) {
  (void)in_sizes; (void)n_in; (void)out_size; (void)ws_size;
  const float* x0 = reinterpret_cast<const float*>(d_in[0]);
  const float* x1 = reinterpret_cast<const float*>(d_in[1]);
  float* out = reinterpret_cast<float*>(d_out);

  float* Rsum = reinterpret_cast<float*>(d_ws);
  float* Csum = Rsum + Ldim;
  float* RM = Csum + Sdim;
  float* CM = RM + Ldim;

  // zero the stats arrays (sums -> 0, maxes of positive floats -> 0)
  hipMemsetAsync(d_ws, 0, sizeof(float) * (size_t)(2 * Ldim + 2 * Sdim), stream);

  k_gemm_mfma<<<(Ldim / BM) * (Sdim / BN), 256, 0, stream>>>(x0, x1, out, Rsum, Csum);
  k_conf_max<<<(Ldim / 64) * (Sdim / 64), 256, 0, stream>>>(out, Rsum, Csum, RM, CM);
  k_mask<<<(Ldim * Sdim) / (4 * 256), 256, 0, stream>>>(out, Rsum, Csum, RM, CM);
}

// Round 3
// 342.897 us; speedup vs baseline: 1.4842x; 1.1301x over previous
//
#include <hip/hip_runtime.h>

namespace {

constexpr int Ldim = 6400;   // rows (h0*w0)
constexpr int Sdim = 6400;   // cols (h1*w1)
constexpr float INV_CT = 0.0390625f;  // 1/(256*0.1), exact
constexpr float THR = 0.2f;

typedef __attribute__((ext_vector_type(8))) short short8;
typedef __attribute__((ext_vector_type(4))) float f32x4;

__device__ __forceinline__ void atomicMaxPosF(float* addr, float v) {
  // valid for non-negative floats: uint bit order == float order
  atomicMax(reinterpret_cast<unsigned int*>(addr), __float_as_uint(v));
}

__device__ __forceinline__ bool valid80(int idx) {
  const int i = idx / 80;
  const int j = idx - i * 80;
  return (i >= 2) & (i < 78) & (j >= 2) & (j < 78);
}

// round-to-nearest-even fp32 -> bf16 bits
__device__ __forceinline__ unsigned short f2bf(float v) {
  unsigned u = __float_as_uint(v);
  return (unsigned short)((u + 0x7fffu + ((u >> 16) & 1u)) >> 16);
}
__device__ __forceinline__ void splitbf(float v, unsigned short& h, unsigned short& l) {
  h = f2bf(v);
  float back = __uint_as_float(((unsigned)h) << 16);
  l = f2bf(v - back);
}

// The ONE conf expression. Must be used identically in k_max and k_out so the
// == tests against reduced maxes are bitwise-consistent.
__device__ __forceinline__ float conf1(float s, float rs, float cs) {
  return expf(2.f * s) / (rs * cs);
}
// The ONE candidate precheck (over-inclusive by 0.05 in log domain).
__device__ __forceinline__ bool precand(float s, float lc, float cu) {
  return 2.f * s - lc > cu;
}

typedef const __attribute__((address_space(1))) unsigned int guint;
typedef __attribute__((address_space(3))) unsigned int suint;
__device__ __forceinline__ void gload16(const void* g, void* l) {
  __builtin_amdgcn_global_load_lds((guint*)g, (suint*)l, 16, 0, 0);
}

// --- P-layout for pre-split bf16 buffers -----------------------------------
// X' = [kstep 0..7][row 0..6399][granule g' 0..3][8 bf16]   (row block = 64 B)
// granule g' of row r holds elements k = kstep*32 + (g' ^ ((r>>1)&3))*8 ..+7.
// This makes (a) global_load_lds staging perfectly linear/coalesced and
// (b) frag ds_read_b128 spread across bank groups (2-way max = free).

// k_split: fp32 -> (hi, lo) bf16 in P-layout. One thread per 8-elem granule.
__global__ __launch_bounds__(256)
void k_split(const float* __restrict__ X, unsigned short* __restrict__ Xh,
             unsigned short* __restrict__ Xl) {
  const int g = blockIdx.x * 256 + threadIdx.x;  // 6400*32 = 204800
  const int r = g >> 5;
  const int gt = g & 31;
  const float* src = X + ((size_t)r << 8) + (gt << 3);
  const float4 a = *reinterpret_cast<const float4*>(src);
  const float4 b = *reinterpret_cast<const float4*>(src + 4);
  unsigned short h[8], l[8];
  splitbf(a.x, h[0], l[0]); splitbf(a.y, h[1], l[1]);
  splitbf(a.z, h[2], l[2]); splitbf(a.w, h[3], l[3]);
  splitbf(b.x, h[4], l[4]); splitbf(b.y, h[5], l[5]);
  splitbf(b.z, h[6], l[6]); splitbf(b.w, h[7], l[7]);
  const int gp = (gt & 3) ^ ((r >> 1) & 3);
  const size_t dst = ((size_t)((gt >> 2) * Ldim + r) * 4 + gp) << 3;
  short8 hv, lv;
#pragma unroll
  for (int i = 0; i < 8; ++i) { hv[i] = (short)h[i]; lv[i] = (short)l[i]; }
  *reinterpret_cast<short8*>(Xh + dst) = hv;
  *reinterpret_cast<short8*>(Xl + dst) = lv;
}

// --- K1: bf16x3 MFMA GEMM, global_load_lds staging from P-layout.
__global__ __launch_bounds__(256)
void k_gemm(const unsigned short* __restrict__ Ah, const unsigned short* __restrict__ Al,
            const unsigned short* __restrict__ Bh, const unsigned short* __restrict__ Bl,
            float* __restrict__ sim, float* __restrict__ Rsum,
            float* __restrict__ Csum) {
  __shared__ unsigned short sAh[4096], sAl[4096], sBh[4096], sBl[4096];

  const int tid = threadIdx.x;
  const int lane = tid & 63;
  const int wave = tid >> 6;
  const int wr = wave >> 1, wc = wave & 1;
  const int bx = blockIdx.x % (Sdim / 128);
  const int by = blockIdx.x / (Sdim / 128);
  const int m0 = by * 128, n0 = bx * 128;

  const int ll = lane & 15;   // frag row/col
  const int lg = lane >> 4;   // frag k-group
  const int arow = lane >> 2; // staging: row within 16-row chunk
  const int gsel = (lane & 3) * 8;  // staging: granule (ushort offset)

  f32x4 acc[4][4];
#pragma unroll
  for (int mi = 0; mi < 4; ++mi)
#pragma unroll
    for (int ni = 0; ni < 4; ++ni) acc[mi][ni] = (f32x4){0.f, 0.f, 0.f, 0.f};

  for (int ks = 0; ks < 8; ++ks) {
    __syncthreads();  // previous readers done before overwrite
    const size_t kb = (size_t)ks * Ldim * 32;
#pragma unroll
    for (int p = 0; p < 2; ++p) {
      const int ch = wave * 2 + p;  // 16-row chunk 0..7
      const size_t asrc = kb + (size_t)(m0 + ch * 16 + arow) * 32 + gsel;
      const size_t bsrc = kb + (size_t)(n0 + ch * 16 + arow) * 32 + gsel;
      gload16(Ah + asrc, &sAh[ch * 512]);
      gload16(Al + asrc, &sAl[ch * 512]);
      gload16(Bh + bsrc, &sBh[ch * 512]);
      gload16(Bl + bsrc, &sBl[ch * 512]);
    }
    __syncthreads();  // compiler drains vmcnt before barrier

    // frag read with the inverse granule swizzle
    auto rd = [&](const unsigned short* S, int row) -> short8 {
      const int gp = lg ^ ((row >> 1) & 3);
      return *reinterpret_cast<const short8*>(&S[(row * 4 + gp) * 8]);
    };

    short8 af[4], bfv[4], tf[4];
#pragma unroll
    for (int mi = 0; mi < 4; ++mi) af[mi] = rd(sAh, wr * 64 + mi * 16 + ll);
#pragma unroll
    for (int ni = 0; ni < 4; ++ni) bfv[ni] = rd(sBh, wc * 64 + ni * 16 + ll);
    // hi*hi
#pragma unroll
    for (int mi = 0; mi < 4; ++mi)
#pragma unroll
      for (int ni = 0; ni < 4; ++ni)
        acc[mi][ni] = __builtin_amdgcn_mfma_f32_16x16x32_bf16(af[mi], bfv[ni], acc[mi][ni], 0, 0, 0);
    // hi*lo
#pragma unroll
    for (int ni = 0; ni < 4; ++ni) tf[ni] = rd(sBl, wc * 64 + ni * 16 + ll);
#pragma unroll
    for (int mi = 0; mi < 4; ++mi)
#pragma unroll
      for (int ni = 0; ni < 4; ++ni)
        acc[mi][ni] = __builtin_amdgcn_mfma_f32_16x16x32_bf16(af[mi], tf[ni], acc[mi][ni], 0, 0, 0);
    // lo*hi
#pragma unroll
    for (int mi = 0; mi < 4; ++mi) tf[mi] = rd(sAl, wr * 64 + mi * 16 + ll);
#pragma unroll
    for (int mi = 0; mi < 4; ++mi)
#pragma unroll
      for (int ni = 0; ni < 4; ++ni)
        acc[mi][ni] = __builtin_amdgcn_mfma_f32_16x16x32_bf16(tf[mi], bfv[ni], acc[mi][ni], 0, 0, 0);
  }

#pragma unroll
  for (int mi = 0; mi < 4; ++mi)
#pragma unroll
    for (int ni = 0; ni < 4; ++ni) acc[mi][ni] *= INV_CT;

  // write sim. C/D layout: col = lane&15, row = (lane>>4)*4 + reg  [m89/m91]
#pragma unroll
  for (int mi = 0; mi < 4; ++mi)
#pragma unroll
    for (int r = 0; r < 4; ++r) {
      const int row = m0 + wr * 64 + mi * 16 + lg * 4 + r;
#pragma unroll
      for (int ni = 0; ni < 4; ++ni) {
        const int col = n0 + wc * 64 + ni * 16 + ll;
        sim[(size_t)row * Sdim + col] = acc[mi][ni][r];
      }
    }

  // exp sums (each exp once; feeds row sum via 16-lane shuffle, col partials)
  float colp[4] = {0.f, 0.f, 0.f, 0.f};
#pragma unroll
  for (int mi = 0; mi < 4; ++mi)
#pragma unroll
    for (int r = 0; r < 4; ++r) {
      float re = 0.f;
#pragma unroll
      for (int ni = 0; ni < 4; ++ni) {
        const float e = expf(acc[mi][ni][r]);
        re += e;
        colp[ni] += e;
      }
      re += __shfl_xor(re, 1);
      re += __shfl_xor(re, 2);
      re += __shfl_xor(re, 4);
      re += __shfl_xor(re, 8);
      if (ll == 0)
        atomicAdd(&Rsum[m0 + wr * 64 + mi * 16 + lg * 4 + r], re);
    }
#pragma unroll
  for (int ni = 0; ni < 4; ++ni) {
    float c = colp[ni];
    c += __shfl_xor(c, 16);
    c += __shfl_xor(c, 32);
    if (lane < 16) atomicAdd(&Csum[n0 + wc * 64 + ni * 16 + lane], c);
  }
}

// --- k_logs: lnC[s] = log(Csum), cut[l] = log(Rsum) + ln(0.2) - slack
__global__ __launch_bounds__(256)
void k_logs(const float* __restrict__ Rsum, const float* __restrict__ Csum,
            float* __restrict__ lnC, float* __restrict__ cut) {
  const int i = blockIdx.x * 256 + threadIdx.x;  // 6400
  lnC[i] = logf(Csum[i]);
  cut[i] = logf(Rsum[i]) + logf(THR) - 0.05f;
}

// --- K2: candidate-sparse row/col conf maxes (exact where it matters:
//         if a row/col max has conf < ~THR no element there can pass anyway).
__global__ __launch_bounds__(256)
void k_max(const float* __restrict__ sim, const float* __restrict__ Rsum,
           const float* __restrict__ Csum, const float* __restrict__ lnC,
           const float* __restrict__ cut, float* __restrict__ RM,
           float* __restrict__ CM) {
  const int g = blockIdx.x * 256 + threadIdx.x;
  const int l = g / 1600;
  const int s0 = (g - l * 1600) * 4;
  const float4 s = *reinterpret_cast<const float4*>(&sim[(size_t)l * Sdim + s0]);
  const float4 lc = *reinterpret_cast<const float4*>(&lnC[s0]);
  const float cu = cut[l];
  const bool c0 = precand(s.x, lc.x, cu), c1 = precand(s.y, lc.y, cu);
  const bool c2 = precand(s.z, lc.z, cu), c3 = precand(s.w, lc.w, cu);
  if (c0 | c1 | c2 | c3) {
    const float rs = Rsum[l];
    if (c0) { const float c = conf1(s.x, rs, Csum[s0 + 0]); atomicMaxPosF(&RM[l], c); atomicMaxPosF(&CM[s0 + 0], c); }
    if (c1) { const float c = conf1(s.y, rs, Csum[s0 + 1]); atomicMaxPosF(&RM[l], c); atomicMaxPosF(&CM[s0 + 1], c); }
    if (c2) { const float c = conf1(s.z, rs, Csum[s0 + 2]); atomicMaxPosF(&RM[l], c); atomicMaxPosF(&CM[s0 + 2], c); }
    if (c3) { const float c = conf1(s.w, rs, Csum[s0 + 3]); atomicMaxPosF(&RM[l], c); atomicMaxPosF(&CM[s0 + 3], c); }
  }
}

// --- K3: same precheck + same conf expression; mask and write output in place.
__global__ __launch_bounds__(256)
void k_out(float* __restrict__ simconf, const float* __restrict__ Rsum,
           const float* __restrict__ Csum, const float* __restrict__ lnC,
           const float* __restrict__ cut, const float* __restrict__ RM,
           const float* __restrict__ CM) {
  const int g = blockIdx.x * 256 + threadIdx.x;
  const int l = g / 1600;
  const int s0 = (g - l * 1600) * 4;
  float* p = &simconf[(size_t)l * Sdim + s0];
  const float4 s = *reinterpret_cast<const float4*>(p);
  const float4 lc = *reinterpret_cast<const float4*>(&lnC[s0]);
  const float cu = cut[l];
  float4 o = make_float4(0.f, 0.f, 0.f, 0.f);
  const bool c0 = precand(s.x, lc.x, cu), c1 = precand(s.y, lc.y, cu);
  const bool c2 = precand(s.z, lc.z, cu), c3 = precand(s.w, lc.w, cu);
  if (c0 | c1 | c2 | c3) {
    const float rs = Rsum[l];
    const float rm = RM[l];
    const bool vl = valid80(l);
    if (c0) { const float c = conf1(s.x, rs, Csum[s0 + 0]); if (vl && valid80(s0 + 0) && c > THR && c == rm && c == CM[s0 + 0]) o.x = c; }
    if (c1) { const float c = conf1(s.y, rs, Csum[s0 + 1]); if (vl && valid80(s0 + 1) && c > THR && c == rm && c == CM[s0 + 1]) o.y = c; }
    if (c2) { const float c = conf1(s.z, rs, Csum[s0 + 2]); if (vl && valid80(s0 + 2) && c > THR && c == rm && c == CM[s0 + 2]) o.z = c; }
    if (c3) { const float c = conf1(s.w, rs, Csum[s0 + 3]); if (vl && valid80(s0 + 3) && c > THR && c == rm && c == CM[s0 + 3]) o.w = c; }
  }
  *reinterpret_cast<float4*>(p) = o;
}

}  // namespace

extern "C" void kernel_launch(void* const* d_in, const int* in_sizes, int n_in,
                              void* d_out, int out_size, void* d_ws, size_t ws_size,
                              hipStream_t stream) {
  (void)in_sizes; (void)n_in; (void)out_size; (void)ws_size;
  const float* x0 = reinterpret_cast<const float*>(d_in[0]);
  const float* x1 = reinterpret_cast<const float*>(d_in[1]);
  float* out = reinterpret_cast<float*>(d_out);

  float* Rsum = reinterpret_cast<float*>(d_ws);
  float* Csum = Rsum + Ldim;
  float* RM = Csum + Sdim;
  float* CM = RM + Ldim;
  float* lnC = CM + Sdim;
  float* cut = lnC + Sdim;
  unsigned short* XAh = reinterpret_cast<unsigned short*>(cut + Ldim);
  const size_t PSZ = (size_t)8 * Ldim * 32;  // ushorts per pre-split buffer
  unsigned short* XAl = XAh + PSZ;
  unsigned short* XBh = XAl + PSZ;
  unsigned short* XBl = XBh + PSZ;

  // zero stats (sums -> 0; RM/CM of positive floats -> 0)
  hipMemsetAsync(d_ws, 0, sizeof(float) * (size_t)(4 * Ldim), stream);

  k_split<<<Ldim * 32 / 256, 256, 0, stream>>>(x0, XAh, XAl);
  k_split<<<Ldim * 32 / 256, 256, 0, stream>>>(x1, XBh, XBl);
  k_gemm<<<(Ldim / 128) * (Sdim / 128), 256, 0, stream>>>(XAh, XAl, XBh, XBl, out, Rsum, Csum);
  k_logs<<<Ldim / 256, 256, 0, stream>>>(Rsum, Csum, lnC, cut);
  k_max<<<(size_t)Ldim * Sdim / (4 * 256), 256, 0, stream>>>(out, Rsum, Csum, lnC, cut, RM, CM);
  k_out<<<(size_t)Ldim * Sdim / (4 * 256), 256, 0, stream>>>(out, Rsum, Csum, lnC, cut, RM, CM);
}

// Round 4
// 283.552 us; speedup vs baseline: 1.7948x; 1.2093x over previous
//
#include <hip/hip_runtime.h>

namespace {

constexpr int Ldim = 6400;   // rows (h0*w0)
constexpr int Sdim = 6400;   // cols (h1*w1)
constexpr float INV_CT = 0.0390625f;  // 1/(256*0.1), exact
constexpr float THR = 0.2f;
constexpr int CAP = 65536;   // candidate capacity; provable bound is <=5*6400/.. ~32K

typedef __attribute__((ext_vector_type(8))) short short8;
typedef __attribute__((ext_vector_type(4))) float f32x4;

__device__ __forceinline__ void atomicMaxPosF(float* addr, float v) {
  // valid for non-negative floats: uint bit order == float order
  atomicMax(reinterpret_cast<unsigned int*>(addr), __float_as_uint(v));
}

__device__ __forceinline__ bool valid80(int idx) {
  const int i = idx / 80;
  const int j = idx - i * 80;
  return (i >= 2) & (i < 78) & (j >= 2) & (j < 78);
}

// round-to-nearest-even fp32 -> bf16 bits
__device__ __forceinline__ unsigned short f2bf(float v) {
  unsigned u = __float_as_uint(v);
  return (unsigned short)((u + 0x7fffu + ((u >> 16) & 1u)) >> 16);
}

// The ONE conf expression (used for candidates, RM/CM, and scatter values —
// all within pass B, so == tests are bitwise-consistent by construction).
__device__ __forceinline__ float conf1(float s, float rs, float cs) {
  return expf(2.f * s) / (rs * cs);
}
// The ONE candidate precheck (over-inclusive by 0.05 in log domain:
// catches every element with conf > 0.2*e^-0.05 ~= 0.19).
__device__ __forceinline__ bool precand(float s, float lc, float cu) {
  return 2.f * s - lc > cu;
}

typedef const __attribute__((address_space(1))) unsigned int guint;
typedef __attribute__((address_space(3))) unsigned int suint;
__device__ __forceinline__ void gload16(const void* g, void* l) {
  __builtin_amdgcn_global_load_lds((guint*)g, (suint*)l, 16, 0, 0);
}

// --- P-layout for pre-split bf16 buffers -----------------------------------
// X' = [kstep 0..7][row 0..6399][granule g' 0..3][8 bf16]   (row block = 64 B)
// granule g' of row r holds elements k = kstep*32 + (g' ^ ((r>>1)&3))*8 ..+7.
// (a) global_load_lds staging is perfectly linear/coalesced; (b) frag
// ds_read_b128 spreads across bank groups (R3 measured: 0 bank conflicts).

// k_split: fp32 -> bf16(hi) in P-layout. One thread per 8-elem granule.
__global__ __launch_bounds__(256)
void k_split(const float* __restrict__ X, unsigned short* __restrict__ Xh) {
  const int g = blockIdx.x * 256 + threadIdx.x;  // 6400*32 = 204800
  const int r = g >> 5;
  const int gt = g & 31;
  const float* src = X + ((size_t)r << 8) + (gt << 3);
  const float4 a = *reinterpret_cast<const float4*>(src);
  const float4 b = *reinterpret_cast<const float4*>(src + 4);
  short8 hv;
  hv[0] = (short)f2bf(a.x); hv[1] = (short)f2bf(a.y);
  hv[2] = (short)f2bf(a.z); hv[3] = (short)f2bf(a.w);
  hv[4] = (short)f2bf(b.x); hv[5] = (short)f2bf(b.y);
  hv[6] = (short)f2bf(b.z); hv[7] = (short)f2bf(b.w);
  const int gp = (gt & 3) ^ ((r >> 1) & 3);
  const size_t dst = ((size_t)((gt >> 2) * Ldim + r) * 4 + gp) << 3;
  *reinterpret_cast<short8*>(Xh + dst) = hv;
}

// --- shared GEMM main loop: 128x128 tile, BK=32, 4 waves (2x2 of 64x64),
//     double-buffered LDS, stage-next-before-compute (2-phase pipeline).
__device__ __forceinline__ void gemm128(
    const unsigned short* __restrict__ A, const unsigned short* __restrict__ B,
    int m0, int n0, int wave, int lane,
    unsigned short (*sA)[4096], unsigned short (*sB)[4096], f32x4 acc[4][4]) {
  const int wr = wave >> 1, wc = wave & 1;
  const int ll = lane & 15;   // frag row/col
  const int lg = lane >> 4;   // frag k-group
  const int arow = lane >> 2; // staging: row within 16-row chunk
  const int gsel = (lane & 3) * 8;  // staging: granule (ushort offset)

#pragma unroll
  for (int mi = 0; mi < 4; ++mi)
#pragma unroll
    for (int ni = 0; ni < 4; ++ni) acc[mi][ni] = (f32x4){0.f, 0.f, 0.f, 0.f};

  auto stage = [&](int slot, int ks) {
    const size_t kb = (size_t)ks * Ldim * 32;
#pragma unroll
    for (int p = 0; p < 2; ++p) {
      const int ch = wave * 2 + p;  // 16-row chunk 0..7
      const size_t asrc = kb + (size_t)(m0 + ch * 16 + arow) * 32 + gsel;
      const size_t bsrc = kb + (size_t)(n0 + ch * 16 + arow) * 32 + gsel;
      gload16(A + asrc, &sA[slot][ch * 512]);
      gload16(B + bsrc, &sB[slot][ch * 512]);
    }
  };

  stage(0, 0);
  __syncthreads();  // compiler drains vmcnt before s_barrier

  for (int ks = 0; ks < 8; ++ks) {
    const int cur = ks & 1;
    if (ks < 7) stage(cur ^ 1, ks + 1);  // prefetch overlaps this tile's MFMA

    auto rd = [&](unsigned short* S, int row) -> short8 {
      const int gp = lg ^ ((row >> 1) & 3);  // inverse granule swizzle
      return *reinterpret_cast<const short8*>(&S[(row * 4 + gp) * 8]);
    };
    short8 af[4], bfv[4];
#pragma unroll
    for (int mi = 0; mi < 4; ++mi) af[mi] = rd(sA[cur], wr * 64 + mi * 16 + ll);
#pragma unroll
    for (int ni = 0; ni < 4; ++ni) bfv[ni] = rd(sB[cur], wc * 64 + ni * 16 + ll);
#pragma unroll
    for (int mi = 0; mi < 4; ++mi)
#pragma unroll
      for (int ni = 0; ni < 4; ++ni)
        acc[mi][ni] = __builtin_amdgcn_mfma_f32_16x16x32_bf16(af[mi], bfv[ni], acc[mi][ni], 0, 0, 0);

    __syncthreads();  // drains prefetch vmcnt + all lgkm before buffer swap
  }

#pragma unroll
  for (int mi = 0; mi < 4; ++mi)
#pragma unroll
    for (int ni = 0; ni < 4; ++ni) acc[mi][ni] *= INV_CT;
}

// --- Pass A: exp-sum stats only (no sim write).
__global__ __launch_bounds__(256)
void k_gemm_stats(const unsigned short* __restrict__ A, const unsigned short* __restrict__ B,
                  float* __restrict__ Rsum, float* __restrict__ Csum) {
  __shared__ unsigned short sA[2][4096], sB[2][4096];
  const int tid = threadIdx.x;
  const int lane = tid & 63, wave = tid >> 6;
  const int bx = blockIdx.x % (Sdim / 128);
  const int by = blockIdx.x / (Sdim / 128);
  const int m0 = by * 128, n0 = bx * 128;
  const int wr = wave >> 1, wc = wave & 1;
  const int ll = lane & 15, lg = lane >> 4;

  f32x4 acc[4][4];
  gemm128(A, B, m0, n0, wave, lane, sA, sB, acc);

  // C/D layout: col = lane&15, row = (lane>>4)*4 + reg  [m89/m91]
  float colp[4] = {0.f, 0.f, 0.f, 0.f};
#pragma unroll
  for (int mi = 0; mi < 4; ++mi)
#pragma unroll
    for (int r = 0; r < 4; ++r) {
      float re = 0.f;
#pragma unroll
      for (int ni = 0; ni < 4; ++ni) {
        const float e = expf(acc[mi][ni][r]);
        re += e;
        colp[ni] += e;
      }
      re += __shfl_xor(re, 1);
      re += __shfl_xor(re, 2);
      re += __shfl_xor(re, 4);
      re += __shfl_xor(re, 8);
      if (ll == 0)
        atomicAdd(&Rsum[m0 + wr * 64 + mi * 16 + lg * 4 + r], re);
    }
#pragma unroll
  for (int ni = 0; ni < 4; ++ni) {
    float c = colp[ni];
    c += __shfl_xor(c, 16);
    c += __shfl_xor(c, 32);
    if (lane < 16) atomicAdd(&Csum[n0 + wc * 64 + ni * 16 + lane], c);
  }
}

// --- k_logs: lnC[s] = log(Csum), cut[l] = log(Rsum) + ln(0.2) - slack
__global__ __launch_bounds__(256)
void k_logs(const float* __restrict__ Rsum, const float* __restrict__ Csum,
            float* __restrict__ lnC, float* __restrict__ cut) {
  const int i = blockIdx.x * 256 + threadIdx.x;  // 6400
  lnC[i] = logf(Csum[i]);
  cut[i] = logf(Rsum[i]) + logf(THR) - 0.05f;
}

// --- Pass B: recompute sim in-register, extract candidates (conf >~ 0.19),
//     update RM/CM maxes and append to compacted candidate list.
//     Exactness: if a row/col max conf < 0.19, nothing there can pass the
//     0.2 threshold anyway, so RM/CM==0 for it is harmless; otherwise the
//     max IS a candidate and RM/CM get the exact value.
__global__ __launch_bounds__(256)
void k_gemm_cand(const unsigned short* __restrict__ A, const unsigned short* __restrict__ B,
                 const float* __restrict__ Rsum, const float* __restrict__ Csum,
                 const float* __restrict__ lnC, const float* __restrict__ cut,
                 float* __restrict__ RM, float* __restrict__ CM,
                 unsigned int* __restrict__ cnt, unsigned int* __restrict__ cidx,
                 float* __restrict__ cconf) {
  __shared__ unsigned short sA[2][4096], sB[2][4096];
  const int tid = threadIdx.x;
  const int lane = tid & 63, wave = tid >> 6;
  const int bx = blockIdx.x % (Sdim / 128);
  const int by = blockIdx.x / (Sdim / 128);
  const int m0 = by * 128, n0 = bx * 128;
  const int wr = wave >> 1, wc = wave & 1;
  const int ll = lane & 15, lg = lane >> 4;

  f32x4 acc[4][4];
  gemm128(A, B, m0, n0, wave, lane, sA, sB, acc);

  float lc[4];
#pragma unroll
  for (int ni = 0; ni < 4; ++ni) lc[ni] = lnC[n0 + wc * 64 + ni * 16 + ll];

#pragma unroll
  for (int mi = 0; mi < 4; ++mi)
#pragma unroll
    for (int r = 0; r < 4; ++r) {
      const int row = m0 + wr * 64 + mi * 16 + lg * 4 + r;
      const float cu = cut[row];
      const bool b0 = precand(acc[mi][0][r], lc[0], cu);
      const bool b1 = precand(acc[mi][1][r], lc[1], cu);
      const bool b2 = precand(acc[mi][2][r], lc[2], cu);
      const bool b3 = precand(acc[mi][3][r], lc[3], cu);
      if (b0 | b1 | b2 | b3) {  // rare path
        const float rs = Rsum[row];
#pragma unroll
        for (int ni = 0; ni < 4; ++ni) {
          const bool b = (ni == 0) ? b0 : (ni == 1) ? b1 : (ni == 2) ? b2 : b3;
          if (b) {
            const int col = n0 + wc * 64 + ni * 16 + ll;
            const float c = conf1(acc[mi][ni][r], rs, Csum[col]);
            atomicMaxPosF(&RM[row], c);
            atomicMaxPosF(&CM[col], c);
            const unsigned t = atomicAdd(cnt, 1u);
            if (t < CAP) {
              cidx[t] = (unsigned)row * Sdim + col;
              cconf[t] = c;
            }
          }
        }
      }
    }
}

// --- k_scatter: final mask over the (tiny) candidate list; writes matches.
__global__ __launch_bounds__(256)
void k_scatter(const unsigned int* __restrict__ cnt, const unsigned int* __restrict__ cidx,
               const float* __restrict__ cconf, const float* __restrict__ RM,
               const float* __restrict__ CM, float* __restrict__ out) {
  const int n = (int)min(*cnt, (unsigned)CAP);
  for (int i = blockIdx.x * 256 + threadIdx.x; i < n; i += gridDim.x * 256) {
    const unsigned idx = cidx[i];
    const int l = idx / Sdim;
    const int s = idx - l * Sdim;
    const float c = cconf[i];
    if (c > THR && valid80(l) && valid80(s) && c == RM[l] && c == CM[s])
      out[idx] = c;
  }
}

}  // namespace

extern "C" void kernel_launch(void* const* d_in, const int* in_sizes, int n_in,
                              void* d_out, int out_size, void* d_ws, size_t ws_size,
                              hipStream_t stream) {
  (void)in_sizes; (void)n_in; (void)out_size; (void)ws_size;
  const float* x0 = reinterpret_cast<const float*>(d_in[0]);
  const float* x1 = reinterpret_cast<const float*>(d_in[1]);
  float* out = reinterpret_cast<float*>(d_out);

  // ws layout: [Rsum 6400][Csum 6400][RM 6400][CM 6400][cnt 4][lnC 6400]
  //            [cut 6400][cidx CAP][cconf CAP][XA][XB]
  float* Rsum = reinterpret_cast<float*>(d_ws);
  float* Csum = Rsum + Ldim;
  float* RM = Csum + Sdim;
  float* CM = RM + Ldim;
  unsigned int* cnt = reinterpret_cast<unsigned int*>(CM + Sdim);
  float* lnC = reinterpret_cast<float*>(cnt + 4);
  float* cut = lnC + Sdim;
  unsigned int* cidx = reinterpret_cast<unsigned int*>(cut + Ldim);
  float* cconf = reinterpret_cast<float*>(cidx + CAP);
  unsigned short* XA = reinterpret_cast<unsigned short*>(cconf + CAP);
  const size_t PSZ = (size_t)8 * Ldim * 32;  // ushorts per pre-split buffer
  unsigned short* XB = XA + PSZ;

  // zero stats + count (sums -> 0; RM/CM of positive floats -> 0)
  hipMemsetAsync(d_ws, 0, sizeof(float) * (size_t)(4 * Ldim) + 16, stream);

  k_split<<<Ldim * 32 / 256, 256, 0, stream>>>(x0, XA);
  k_split<<<Ldim * 32 / 256, 256, 0, stream>>>(x1, XB);
  k_gemm_stats<<<(Ldim / 128) * (Sdim / 128), 256, 0, stream>>>(XA, XB, Rsum, Csum);
  k_logs<<<Ldim / 256, 256, 0, stream>>>(Rsum, Csum, lnC, cut);
  k_gemm_cand<<<(Ldim / 128) * (Sdim / 128), 256, 0, stream>>>(
      XA, XB, Rsum, Csum, lnC, cut, RM, CM, cnt, cidx, cconf);
  hipMemsetAsync(out, 0, sizeof(float) * (size_t)Ldim * Sdim, stream);
  k_scatter<<<64, 256, 0, stream>>>(cnt, cidx, cconf, RM, CM, out);
}